// Round 2
// baseline (352.327 us; speedup 1.0000x reference)
//
#include <hip/hip_runtime.h>
#include <hip/hip_bf16.h>
#include <cstdint>

// ---------------- CSR build ----------------
// NOTE: harness passes integer inputs as int32 (edge_index values < 2^31).

__global__ __launch_bounds__(256) void k_init(int* cnt, int* cursor, int n) {
  int i = blockIdx.x * 256 + threadIdx.x;
  if (i < n) { cnt[i] = 1; cursor[i] = 0; }  // cnt starts at 1 for the self-loop
}

__global__ __launch_bounds__(256) void k_count(const int* __restrict__ ei,
                                               int* __restrict__ cnt, int E) {
  int e = blockIdx.x * 256 + threadIdx.x;
  if (e < E) atomicAdd(&cnt[ei[E + e]], 1);
}

__global__ __launch_bounds__(1024) void k_bsum(const int* __restrict__ cnt,
                                               int* __restrict__ bsum, int n) {
  __shared__ int ws_[16];
  int i = blockIdx.x * 1024 + threadIdx.x;
  int v = (i < n) ? cnt[i] : 0;
#pragma unroll
  for (int d = 1; d < 64; d <<= 1) v += __shfl_xor(v, d);
  int lane = threadIdx.x & 63, wid = threadIdx.x >> 6;
  if (lane == 0) ws_[wid] = v;
  __syncthreads();
  if (threadIdx.x == 0) {
    int s = 0;
#pragma unroll
    for (int j = 0; j < 16; ++j) s += ws_[j];
    bsum[blockIdx.x] = s;
  }
}

// single-wave exclusive scan of block sums (nb <= 64 for N=50000)
__global__ __launch_bounds__(64) void k_scanb(int* bsum, int* off, int nb, int n) {
  int t = threadIdx.x;
  int v = (t < nb) ? bsum[t] : 0;
  int orig = v;
#pragma unroll
  for (int d = 1; d < 64; d <<= 1) {
    int u = __shfl_up(v, d, 64);
    if (t >= d) v += u;
  }
  if (t < nb) bsum[t] = v - orig;   // exclusive block offset
  if (t == 63) off[n] = v;          // grand total
}

__global__ __launch_bounds__(1024) void k_scanc(const int* __restrict__ cnt,
                                                const int* __restrict__ bsum,
                                                int* __restrict__ off, int n) {
  __shared__ int wsum[16];
  int i = blockIdx.x * 1024 + threadIdx.x;
  int v = (i < n) ? cnt[i] : 0;
  int orig = v;
  int lane = threadIdx.x & 63, wid = threadIdx.x >> 6;
#pragma unroll
  for (int d = 1; d < 64; d <<= 1) {
    int u = __shfl_up(v, d, 64);
    if (lane >= d) v += u;
  }
  if (lane == 63) wsum[wid] = v;
  __syncthreads();
  if (wid == 0) {
    int s = (lane < 16) ? wsum[lane] : 0;
#pragma unroll
    for (int d = 1; d < 16; d <<= 1) {
      int u = __shfl_up(s, d, 64);
      if (lane >= d) s += u;
    }
    if (lane < 16) wsum[lane] = s;
  }
  __syncthreads();
  if (wid > 0) v += wsum[wid - 1];
  if (i < n) off[i] = bsum[blockIdx.x] + v - orig;  // exclusive
}

__global__ __launch_bounds__(256) void k_scatter(const int* __restrict__ ei,
                                                 const int* __restrict__ off,
                                                 int* __restrict__ cursor,
                                                 int* __restrict__ adj, int E, int n) {
  int idx = blockIdx.x * 256 + threadIdx.x;
  if (idx < E) {
    int s = ei[idx];
    int d = ei[E + idx];
    int pos = off[d] + atomicAdd(&cursor[d], 1);
    adj[pos] = s;
  } else if (idx < E + n) {
    int i = idx - E;
    int pos = off[i] + atomicAdd(&cursor[i], 1);
    adj[pos] = i;  // self loop
  }
}

// ---------------- GEMM1: h1 = x @ W1, fused alpha_src/alpha_dst ----------------
// block 256, 64-row x tiles in LDS; W staged in four 32-row K-chunks (<= 50KB static LDS)

__global__ __launch_bounds__(256) void k_gemm1(const float* __restrict__ x,
                                               const float* __restrict__ W,
                                               const float* __restrict__ a_src,
                                               const float* __restrict__ a_dst,
                                               float* __restrict__ h1,
                                               float* __restrict__ as1,
                                               float* __restrict__ ad1, int n) {
  __shared__ float xs[64][132];       // 33.8 KB (padded: +4 to break stride-128 banks)
  __shared__ float wbuf[32 * 128];    // 16 KB: one 32-row K-chunk of W
  int t = threadIdx.x;
  int tr = t >> 5, tc = t & 31;
  int head = tc >> 3;  // columns tc*4..tc*4+3 all belong to head tc>>3
  float a_s[4], a_d[4];
#pragma unroll
  for (int ci = 0; ci < 4; ++ci) {
    int dcol = (tc * 4 + ci) & 31;
    a_s[ci] = a_src[head * 32 + dcol];
    a_d[ci] = a_dst[head * 32 + dcol];
  }
  int ntiles = (n + 63) >> 6;
  for (int tile = blockIdx.x; tile < ntiles; tile += gridDim.x) {
    int row0 = tile << 6;
    __syncthreads();  // previous iteration's readers done before overwrite
#pragma unroll
    for (int rr = 0; rr < 64; rr += 8) {
      int r = rr + tr;
      int gr = row0 + r;
      float4 v = make_float4(0.f, 0.f, 0.f, 0.f);
      if (gr < n) v = *(const float4*)&x[(size_t)gr * 128 + tc * 4];
      *(float4*)&xs[r][tc * 4] = v;
    }
    float acc[8][4] = {};
#pragma unroll
    for (int kt = 0; kt < 4; ++kt) {
      __syncthreads();  // kt=0: xs visible + prev wbuf readers done; kt>0: prev chunk read done
#pragma unroll
      for (int i = t * 4; i < 32 * 128; i += 1024)
        *(float4*)&wbuf[i] = *(const float4*)&W[kt * 32 * 128 + i];
      __syncthreads();
#pragma unroll 8
      for (int k = 0; k < 32; ++k) {
        float4 wv = *(float4*)&wbuf[k * 128 + tc * 4];
#pragma unroll
        for (int ri = 0; ri < 8; ++ri) {
          float xv = xs[tr * 8 + ri][kt * 32 + k];
          acc[ri][0] += xv * wv.x;
          acc[ri][1] += xv * wv.y;
          acc[ri][2] += xv * wv.z;
          acc[ri][3] += xv * wv.w;
        }
      }
    }
#pragma unroll
    for (int ri = 0; ri < 8; ++ri) {
      int gr = row0 + tr * 8 + ri;
      float ps = acc[ri][0] * a_s[0] + acc[ri][1] * a_s[1] +
                 acc[ri][2] * a_s[2] + acc[ri][3] * a_s[3];
      float pd = acc[ri][0] * a_d[0] + acc[ri][1] * a_d[1] +
                 acc[ri][2] * a_d[2] + acc[ri][3] * a_d[3];
      // reduce over the 8 consecutive-tc threads covering this head's 32 cols
      ps += __shfl_xor(ps, 1); ps += __shfl_xor(ps, 2); ps += __shfl_xor(ps, 4);
      pd += __shfl_xor(pd, 1); pd += __shfl_xor(pd, 2); pd += __shfl_xor(pd, 4);
      if (gr < n) {
        *(float4*)&h1[(size_t)gr * 128 + tc * 4] =
            make_float4(acc[ri][0], acc[ri][1], acc[ri][2], acc[ri][3]);
        if ((tc & 7) == 0) {
          as1[gr * 4 + head] = ps;
          ad1[gr * 4 + head] = pd;
        }
      }
    }
  }
}

// ---------------- conv1 aggregation: wave per dst node ----------------

__global__ __launch_bounds__(256) void k_conv1(const int* __restrict__ off,
                                               const int* __restrict__ adj,
                                               const float* __restrict__ h1,
                                               const float* __restrict__ as1,
                                               const float* __restrict__ ad1,
                                               const float* __restrict__ b1,
                                               float* __restrict__ x2, int n) {
  int node = (blockIdx.x * 256 + threadIdx.x) >> 6;
  int lane = threadIdx.x & 63;
  if (node >= n) return;
  int beg = off[node], end = off[node + 1];
  const float4 adv = *(const float4*)&ad1[node * 4];
  float m0 = -1e30f, m1 = -1e30f, m2 = -1e30f, m3 = -1e30f;
  float z0 = 0.f, z1 = 0.f, z2 = 0.f, z3 = 0.f;
  for (int e = beg + lane; e < end; e += 64) {
    int s = adj[e];
    float4 av = *(const float4*)&as1[s * 4];
    float v, nm;
    v = av.x + adv.x; v = v > 0.f ? v : 0.2f * v;
    nm = fmaxf(m0, v); z0 = z0 * __expf(m0 - nm) + __expf(v - nm); m0 = nm;
    v = av.y + adv.y; v = v > 0.f ? v : 0.2f * v;
    nm = fmaxf(m1, v); z1 = z1 * __expf(m1 - nm) + __expf(v - nm); m1 = nm;
    v = av.z + adv.z; v = v > 0.f ? v : 0.2f * v;
    nm = fmaxf(m2, v); z2 = z2 * __expf(m2 - nm) + __expf(v - nm); m2 = nm;
    v = av.w + adv.w; v = v > 0.f ? v : 0.2f * v;
    nm = fmaxf(m3, v); z3 = z3 * __expf(m3 - nm) + __expf(v - nm); m3 = nm;
  }
#pragma unroll
  for (int d = 1; d < 64; d <<= 1) {
    float om, oz, nm;
    om = __shfl_xor(m0, d); oz = __shfl_xor(z0, d);
    nm = fmaxf(m0, om); z0 = z0 * __expf(m0 - nm) + oz * __expf(om - nm); m0 = nm;
    om = __shfl_xor(m1, d); oz = __shfl_xor(z1, d);
    nm = fmaxf(m1, om); z1 = z1 * __expf(m1 - nm) + oz * __expf(om - nm); m1 = nm;
    om = __shfl_xor(m2, d); oz = __shfl_xor(z2, d);
    nm = fmaxf(m2, om); z2 = z2 * __expf(m2 - nm) + oz * __expf(om - nm); m2 = nm;
    om = __shfl_xor(m3, d); oz = __shfl_xor(z3, d);
    nm = fmaxf(m3, om); z3 = z3 * __expf(m3 - nm) + oz * __expf(om - nm); m3 = nm;
  }
  // accumulate: lanes over channels (2 per lane), serial over edges
  int hh = lane >> 4;  // head owning channels 2*lane, 2*lane+1
  float mm  = hh == 0 ? m0 : hh == 1 ? m1 : hh == 2 ? m2 : m3;
  float zz  = hh == 0 ? z0 : hh == 1 ? z1 : hh == 2 ? z2 : z3;
  float adh = hh == 0 ? adv.x : hh == 1 ? adv.y : hh == 2 ? adv.z : adv.w;
  float inv = 1.0f / (zz + 1e-16f);
  float accx = 0.f, accy = 0.f;
  int c0 = lane * 2;
  for (int e = beg; e < end; ++e) {
    int s = adj[e];
    float v = as1[s * 4 + hh] + adh;
    v = v > 0.f ? v : 0.2f * v;
    float wgt = __expf(v - mm) * inv;
    float2 hv = *(const float2*)&h1[(size_t)s * 128 + c0];
    accx += wgt * hv.x;
    accy += wgt * hv.y;
  }
  float o0 = accx + b1[c0], o1 = accy + b1[c0 + 1];
  o0 = o0 > 0.f ? o0 : __expf(o0) - 1.f;  // ELU fused
  o1 = o1 > 0.f ? o1 : __expf(o1) - 1.f;
  *(float2*)&x2[(size_t)node * 128 + c0] = make_float2(o0, o1);
}

// ---------------- GEMM2: h2 = x2 @ W2 (+ alpha projections), wave per row ----------------

__global__ __launch_bounds__(256) void k_gemm2(const float* __restrict__ x2,
                                               const float* __restrict__ W2,
                                               const float* __restrict__ a_src,
                                               const float* __restrict__ a_dst,
                                               float* __restrict__ h2,
                                               float* __restrict__ as2,
                                               float* __restrict__ ad2, int n) {
  int gw = (blockIdx.x * 256 + threadIdx.x) >> 6;
  int lane = threadIdx.x & 63;
  if (gw >= n) return;
  float2 xv = *(const float2*)&x2[(size_t)gw * 128 + lane * 2];
  const float* w0 = &W2[(lane * 2) * 10];
  float r[10];
#pragma unroll
  for (int c = 0; c < 10; ++c) {
    float p = xv.x * w0[c] + xv.y * w0[10 + c];
#pragma unroll
    for (int d = 1; d < 64; d <<= 1) p += __shfl_xor(p, d);
    r[c] = p;
  }
  if (lane == 0) {
    float s = 0.f, ds = 0.f;
#pragma unroll
    for (int c = 0; c < 10; ++c) {
      h2[(size_t)gw * 10 + c] = r[c];
      s += r[c] * a_src[c];
      ds += r[c] * a_dst[c];
    }
    as2[gw] = s;
    ad2[gw] = ds;
  }
}

// ---------------- conv2 aggregation: wave per dst node ----------------

__global__ __launch_bounds__(256) void k_conv2(const int* __restrict__ off,
                                               const int* __restrict__ adj,
                                               const float* __restrict__ h2,
                                               const float* __restrict__ as2,
                                               const float* __restrict__ ad2,
                                               const float* __restrict__ b2,
                                               float* __restrict__ out, int n) {
  int node = (blockIdx.x * 256 + threadIdx.x) >> 6;
  int lane = threadIdx.x & 63;
  if (node >= n) return;
  int beg = off[node], end = off[node + 1];
  float adv = ad2[node];
  float m = -1e30f, z = 0.f;
  for (int e = beg + lane; e < end; e += 64) {
    int s = adj[e];
    float v = as2[s] + adv;
    v = v > 0.f ? v : 0.2f * v;
    float nm = fmaxf(m, v);
    z = z * __expf(m - nm) + __expf(v - nm);
    m = nm;
  }
#pragma unroll
  for (int d = 1; d < 64; d <<= 1) {
    float om = __shfl_xor(m, d), oz = __shfl_xor(z, d);
    float nm = fmaxf(m, om);
    z = z * __expf(m - nm) + oz * __expf(om - nm);
    m = nm;
  }
  float inv = 1.0f / (z + 1e-16f);
  float acc[10] = {};
  for (int e = beg + lane; e < end; e += 64) {
    int s = adj[e];
    float v = as2[s] + adv;
    v = v > 0.f ? v : 0.2f * v;
    float wgt = __expf(v - m) * inv;
    const float* hp = &h2[(size_t)s * 10];
#pragma unroll
    for (int c = 0; c < 10; ++c) acc[c] += wgt * hp[c];
  }
#pragma unroll
  for (int c = 0; c < 10; ++c) {
#pragma unroll
    for (int d = 1; d < 64; d <<= 1) acc[c] += __shfl_xor(acc[c], d);
  }
  if (lane == 0) {
#pragma unroll
    for (int c = 0; c < 10; ++c) out[(size_t)node * 10 + c] = acc[c] + b2[c];
  }
}

// ---------------- launch ----------------

extern "C" void kernel_launch(void* const* d_in, const int* in_sizes, int n_in,
                              void* d_out, int out_size, void* d_ws, size_t ws_size,
                              hipStream_t stream) {
  const float* x      = (const float*)d_in[0];
  const int* ei       = (const int*)d_in[1];   // int32: harness converts integer inputs
  const float* W1     = (const float*)d_in[2];
  const float* a_src1 = (const float*)d_in[3];
  const float* a_dst1 = (const float*)d_in[4];
  const float* b1     = (const float*)d_in[5];
  const float* W2     = (const float*)d_in[6];
  const float* a_src2 = (const float*)d_in[7];
  const float* a_dst2 = (const float*)d_in[8];
  const float* b2     = (const float*)d_in[9];
  float* out = (float*)d_out;
  const int N = in_sizes[0] / 128;
  const int E = in_sizes[1] / 2;

  char* ws = (char*)d_ws;
  size_t o = 0;
  auto alloc = [&](size_t bytes) -> void* {
    void* p = ws + o;
    o += (bytes + 255) & ~(size_t)255;
    return p;
  };
  int* cnt    = (int*)alloc((size_t)N * 4);
  int* cursor = (int*)alloc((size_t)N * 4);
  int* offs   = (int*)alloc((size_t)(N + 1) * 4);
  int* bsum   = (int*)alloc(1024 * 4);
  int* adj    = (int*)alloc((size_t)(E + N) * 4);
  float* h1   = (float*)alloc((size_t)N * 128 * 4);
  float* a_s1 = (float*)alloc((size_t)N * 4 * 4);
  float* a_d1 = (float*)alloc((size_t)N * 4 * 4);
  float* x2   = (float*)alloc((size_t)N * 128 * 4);
  float* h2   = (float*)alloc((size_t)N * 10 * 4);
  float* a_s2 = (float*)alloc((size_t)N * 4);
  float* a_d2 = (float*)alloc((size_t)N * 4);

  int nb = (N + 1023) / 1024;
  k_init<<<(N + 255) / 256, 256, 0, stream>>>(cnt, cursor, N);
  k_count<<<(E + 255) / 256, 256, 0, stream>>>(ei, cnt, E);
  k_bsum<<<nb, 1024, 0, stream>>>(cnt, bsum, N);
  k_scanb<<<1, 64, 0, stream>>>(bsum, offs, nb, N);
  k_scanc<<<nb, 1024, 0, stream>>>(cnt, bsum, offs, N);
  k_scatter<<<(E + N + 255) / 256, 256, 0, stream>>>(ei, offs, cursor, adj, E, N);
  k_gemm1<<<256, 256, 0, stream>>>(x, W1, a_src1, a_dst1, h1, a_s1, a_d1, N);
  k_conv1<<<(N + 3) / 4, 256, 0, stream>>>(offs, adj, h1, a_s1, a_d1, b1, x2, N);
  k_gemm2<<<(N + 3) / 4, 256, 0, stream>>>(x2, W2, a_src2, a_dst2, h2, a_s2, a_d2, N);
  k_conv2<<<(N + 3) / 4, 256, 0, stream>>>(offs, adj, h2, a_s2, a_d2, b2, out, N);
}

// Round 3
// 262.674 us; speedup vs baseline: 1.3413x; 1.3413x over previous
//
#include <hip/hip_runtime.h>
#include <hip/hip_bf16.h>
#include <cstdint>

// ---------------- CSR build ----------------
// NOTE: harness passes integer inputs as int32.

__global__ __launch_bounds__(256) void k_init(int* cnt, int* cursor, int n) {
  int i = blockIdx.x * 256 + threadIdx.x;
  if (i < n) { cnt[i] = 1; cursor[i] = 0; }  // cnt starts at 1 for the self-loop
}

__global__ __launch_bounds__(256) void k_count(const int* __restrict__ ei,
                                               int* __restrict__ cnt, int E) {
  int e = blockIdx.x * 256 + threadIdx.x;
  if (e < E) atomicAdd(&cnt[ei[E + e]], 1);
}

__global__ __launch_bounds__(1024) void k_bsum(const int* __restrict__ cnt,
                                               int* __restrict__ bsum, int n) {
  __shared__ int ws_[16];
  int i = blockIdx.x * 1024 + threadIdx.x;
  int v = (i < n) ? cnt[i] : 0;
#pragma unroll
  for (int d = 1; d < 64; d <<= 1) v += __shfl_xor(v, d);
  int lane = threadIdx.x & 63, wid = threadIdx.x >> 6;
  if (lane == 0) ws_[wid] = v;
  __syncthreads();
  if (threadIdx.x == 0) {
    int s = 0;
#pragma unroll
    for (int j = 0; j < 16; ++j) s += ws_[j];
    bsum[blockIdx.x] = s;
  }
}

// single-wave exclusive scan of block sums (nb <= 64 for N=50000)
__global__ __launch_bounds__(64) void k_scanb(int* bsum, int* off, int nb, int n) {
  int t = threadIdx.x;
  int v = (t < nb) ? bsum[t] : 0;
  int orig = v;
#pragma unroll
  for (int d = 1; d < 64; d <<= 1) {
    int u = __shfl_up(v, d, 64);
    if (t >= d) v += u;
  }
  if (t < nb) bsum[t] = v - orig;   // exclusive block offset
  if (t == 63) off[n] = v;          // grand total
}

__global__ __launch_bounds__(1024) void k_scanc(const int* __restrict__ cnt,
                                                const int* __restrict__ bsum,
                                                int* __restrict__ off, int n) {
  __shared__ int wsum[16];
  int i = blockIdx.x * 1024 + threadIdx.x;
  int v = (i < n) ? cnt[i] : 0;
  int orig = v;
  int lane = threadIdx.x & 63, wid = threadIdx.x >> 6;
#pragma unroll
  for (int d = 1; d < 64; d <<= 1) {
    int u = __shfl_up(v, d, 64);
    if (lane >= d) v += u;
  }
  if (lane == 63) wsum[wid] = v;
  __syncthreads();
  if (wid == 0) {
    int s = (lane < 16) ? wsum[lane] : 0;
#pragma unroll
    for (int d = 1; d < 16; d <<= 1) {
      int u = __shfl_up(s, d, 64);
      if (lane >= d) s += u;
    }
    if (lane < 16) wsum[lane] = s;
  }
  __syncthreads();
  if (wid > 0) v += wsum[wid - 1];
  if (i < n) off[i] = bsum[blockIdx.x] + v - orig;  // exclusive
}

__global__ __launch_bounds__(256) void k_scatter(const int* __restrict__ ei,
                                                 const int* __restrict__ off,
                                                 int* __restrict__ cursor,
                                                 int* __restrict__ adj, int E, int n) {
  int idx = blockIdx.x * 256 + threadIdx.x;
  if (idx < E) {
    int s = ei[idx];
    int d = ei[E + idx];
    int pos = off[d] + atomicAdd(&cursor[d], 1);
    adj[pos] = s;
  } else if (idx < E + n) {
    int i = idx - E;
    int pos = off[i] + atomicAdd(&cursor[i], 1);
    adj[pos] = i;  // self loop
  }
}

// ---------------- GEMM1: h1 = x @ W1, fused alpha_src/alpha_dst ----------------

__global__ __launch_bounds__(256) void k_gemm1(const float* __restrict__ x,
                                               const float* __restrict__ W,
                                               const float* __restrict__ a_src,
                                               const float* __restrict__ a_dst,
                                               float* __restrict__ h1,
                                               float* __restrict__ as1,
                                               float* __restrict__ ad1, int n) {
  __shared__ float xs[64][132];       // 33.8 KB (padded)
  __shared__ float wbuf[32 * 128];    // 16 KB: one 32-row K-chunk of W
  int t = threadIdx.x;
  int tr = t >> 5, tc = t & 31;
  int head = tc >> 3;
  float a_s[4], a_d[4];
#pragma unroll
  for (int ci = 0; ci < 4; ++ci) {
    int dcol = (tc * 4 + ci) & 31;
    a_s[ci] = a_src[head * 32 + dcol];
    a_d[ci] = a_dst[head * 32 + dcol];
  }
  int ntiles = (n + 63) >> 6;
  for (int tile = blockIdx.x; tile < ntiles; tile += gridDim.x) {
    int row0 = tile << 6;
    __syncthreads();
#pragma unroll
    for (int rr = 0; rr < 64; rr += 8) {
      int r = rr + tr;
      int gr = row0 + r;
      float4 v = make_float4(0.f, 0.f, 0.f, 0.f);
      if (gr < n) v = *(const float4*)&x[(size_t)gr * 128 + tc * 4];
      *(float4*)&xs[r][tc * 4] = v;
    }
    float acc[8][4] = {};
#pragma unroll
    for (int kt = 0; kt < 4; ++kt) {
      __syncthreads();
#pragma unroll
      for (int i = t * 4; i < 32 * 128; i += 1024)
        *(float4*)&wbuf[i] = *(const float4*)&W[kt * 32 * 128 + i];
      __syncthreads();
#pragma unroll 8
      for (int k = 0; k < 32; ++k) {
        float4 wv = *(float4*)&wbuf[k * 128 + tc * 4];
#pragma unroll
        for (int ri = 0; ri < 8; ++ri) {
          float xv = xs[tr * 8 + ri][kt * 32 + k];
          acc[ri][0] += xv * wv.x;
          acc[ri][1] += xv * wv.y;
          acc[ri][2] += xv * wv.z;
          acc[ri][3] += xv * wv.w;
        }
      }
    }
#pragma unroll
    for (int ri = 0; ri < 8; ++ri) {
      int gr = row0 + tr * 8 + ri;
      float ps = acc[ri][0] * a_s[0] + acc[ri][1] * a_s[1] +
                 acc[ri][2] * a_s[2] + acc[ri][3] * a_s[3];
      float pd = acc[ri][0] * a_d[0] + acc[ri][1] * a_d[1] +
                 acc[ri][2] * a_d[2] + acc[ri][3] * a_d[3];
      ps += __shfl_xor(ps, 1); ps += __shfl_xor(ps, 2); ps += __shfl_xor(ps, 4);
      pd += __shfl_xor(pd, 1); pd += __shfl_xor(pd, 2); pd += __shfl_xor(pd, 4);
      if (gr < n) {
        *(float4*)&h1[(size_t)gr * 128 + tc * 4] =
            make_float4(acc[ri][0], acc[ri][1], acc[ri][2], acc[ri][3]);
        if ((tc & 7) == 0) {
          as1[gr * 4 + head] = ps;
          ad1[gr * 4 + head] = pd;
        }
      }
    }
  }
}

// ---------------- conv1 aggregation: 4 nodes per wave, 16 lanes per node ----------------

__global__ __launch_bounds__(256) void k_conv1(const int* __restrict__ off,
                                               const int* __restrict__ adj,
                                               const float* __restrict__ h1,
                                               const float* __restrict__ as1,
                                               const float* __restrict__ ad1,
                                               const float* __restrict__ b1,
                                               float* __restrict__ x2, int n) {
  int wid = (blockIdx.x * 256 + threadIdx.x) >> 6;  // global wave id
  int lane = threadIdx.x & 63;
  int grp = lane >> 4;       // node slot within wave
  int l16 = lane & 15;
  int node = wid * 4 + grp;
  bool active = node < n;
  int beg = 0, end = 0;
  float4 adv = make_float4(0.f, 0.f, 0.f, 0.f);
  if (active) {
    beg = off[node];
    end = off[node + 1];
    adv = *(const float4*)&ad1[node * 4];
  }
  // phase 1: online softmax (m,z) per head; lanes l16 stride 16 over edges
  float m0 = -1e30f, m1 = -1e30f, m2 = -1e30f, m3 = -1e30f;
  float z0 = 0.f, z1 = 0.f, z2 = 0.f, z3 = 0.f;
  for (int e = beg + l16; e < end; e += 16) {
    int s = adj[e];
    float4 av = *(const float4*)&as1[s * 4];
    float v, nm;
    v = av.x + adv.x; v = v > 0.f ? v : 0.2f * v;
    nm = fmaxf(m0, v); z0 = z0 * __expf(m0 - nm) + __expf(v - nm); m0 = nm;
    v = av.y + adv.y; v = v > 0.f ? v : 0.2f * v;
    nm = fmaxf(m1, v); z1 = z1 * __expf(m1 - nm) + __expf(v - nm); m1 = nm;
    v = av.z + adv.z; v = v > 0.f ? v : 0.2f * v;
    nm = fmaxf(m2, v); z2 = z2 * __expf(m2 - nm) + __expf(v - nm); m2 = nm;
    v = av.w + adv.w; v = v > 0.f ? v : 0.2f * v;
    nm = fmaxf(m3, v); z3 = z3 * __expf(m3 - nm) + __expf(v - nm); m3 = nm;
  }
#pragma unroll
  for (int d = 1; d < 16; d <<= 1) {  // butterfly within 16-lane group
    float om, oz, nm;
    om = __shfl_xor(m0, d); oz = __shfl_xor(z0, d);
    nm = fmaxf(m0, om); z0 = z0 * __expf(m0 - nm) + oz * __expf(om - nm); m0 = nm;
    om = __shfl_xor(m1, d); oz = __shfl_xor(z1, d);
    nm = fmaxf(m1, om); z1 = z1 * __expf(m1 - nm) + oz * __expf(om - nm); m1 = nm;
    om = __shfl_xor(m2, d); oz = __shfl_xor(z2, d);
    nm = fmaxf(m2, om); z2 = z2 * __expf(m2 - nm) + oz * __expf(om - nm); m2 = nm;
    om = __shfl_xor(m3, d); oz = __shfl_xor(z3, d);
    nm = fmaxf(m3, om); z3 = z3 * __expf(m3 - nm) + oz * __expf(om - nm); m3 = nm;
  }
  // phase 2: lanes over channels (8 per lane), serial over this node's edges.
  int hh = l16 >> 2;  // channels l16*8..l16*8+7 all in head l16>>2
  float mm  = hh == 0 ? m0 : hh == 1 ? m1 : hh == 2 ? m2 : m3;
  float zz  = hh == 0 ? z0 : hh == 1 ? z1 : hh == 2 ? z2 : z3;
  float adh = hh == 0 ? adv.x : hh == 1 ? adv.y : hh == 2 ? adv.z : adv.w;
  float inv = 1.0f / (zz + 1e-16f);
  int c0 = l16 * 8;
  float4 acc0 = make_float4(0.f, 0.f, 0.f, 0.f);
  float4 acc1 = make_float4(0.f, 0.f, 0.f, 0.f);
  int e = beg;
  for (; e + 1 < end; e += 2) {  // 2x unroll: more gathers in flight
    int s0 = adj[e], s1 = adj[e + 1];
    float v0 = as1[s0 * 4 + hh] + adh;
    float v1 = as1[s1 * 4 + hh] + adh;
    v0 = v0 > 0.f ? v0 : 0.2f * v0;
    v1 = v1 > 0.f ? v1 : 0.2f * v1;
    float w0 = __expf(v0 - mm) * inv;
    float w1 = __expf(v1 - mm) * inv;
    const float4* p0 = (const float4*)&h1[(size_t)s0 * 128 + c0];
    const float4* p1 = (const float4*)&h1[(size_t)s1 * 128 + c0];
    float4 a0 = p0[0], b0 = p0[1];
    float4 a1 = p1[0], b1v = p1[1];
    acc0.x += w0 * a0.x + w1 * a1.x;  acc0.y += w0 * a0.y + w1 * a1.y;
    acc0.z += w0 * a0.z + w1 * a1.z;  acc0.w += w0 * a0.w + w1 * a1.w;
    acc1.x += w0 * b0.x + w1 * b1v.x; acc1.y += w0 * b0.y + w1 * b1v.y;
    acc1.z += w0 * b0.z + w1 * b1v.z; acc1.w += w0 * b0.w + w1 * b1v.w;
  }
  if (e < end) {
    int s0 = adj[e];
    float v0 = as1[s0 * 4 + hh] + adh;
    v0 = v0 > 0.f ? v0 : 0.2f * v0;
    float w0 = __expf(v0 - mm) * inv;
    const float4* p0 = (const float4*)&h1[(size_t)s0 * 128 + c0];
    float4 a0 = p0[0], b0 = p0[1];
    acc0.x += w0 * a0.x; acc0.y += w0 * a0.y; acc0.z += w0 * a0.z; acc0.w += w0 * a0.w;
    acc1.x += w0 * b0.x; acc1.y += w0 * b0.y; acc1.z += w0 * b0.z; acc1.w += w0 * b0.w;
  }
  if (active) {
    float4 bb0 = *(const float4*)&b1[c0];
    float4 bb1 = *(const float4*)&b1[c0 + 4];
    float o[8] = {acc0.x + bb0.x, acc0.y + bb0.y, acc0.z + bb0.z, acc0.w + bb0.w,
                  acc1.x + bb1.x, acc1.y + bb1.y, acc1.z + bb1.z, acc1.w + bb1.w};
#pragma unroll
    for (int j = 0; j < 8; ++j) o[j] = o[j] > 0.f ? o[j] : __expf(o[j]) - 1.f;  // ELU
    *(float4*)&x2[(size_t)node * 128 + c0]     = make_float4(o[0], o[1], o[2], o[3]);
    *(float4*)&x2[(size_t)node * 128 + c0 + 4] = make_float4(o[4], o[5], o[6], o[7]);
  }
}

// ---------------- GEMM2: h2 = x2 @ W2 (+ alpha projections), wave per row ----------------

__global__ __launch_bounds__(256) void k_gemm2(const float* __restrict__ x2,
                                               const float* __restrict__ W2,
                                               const float* __restrict__ a_src,
                                               const float* __restrict__ a_dst,
                                               float* __restrict__ h2,
                                               float* __restrict__ as2,
                                               float* __restrict__ ad2, int n) {
  int gw = (blockIdx.x * 256 + threadIdx.x) >> 6;
  int lane = threadIdx.x & 63;
  if (gw >= n) return;
  float2 xv = *(const float2*)&x2[(size_t)gw * 128 + lane * 2];
  const float* w0 = &W2[(lane * 2) * 10];
  float r[10];
#pragma unroll
  for (int c = 0; c < 10; ++c) {
    float p = xv.x * w0[c] + xv.y * w0[10 + c];
#pragma unroll
    for (int d = 1; d < 64; d <<= 1) p += __shfl_xor(p, d);
    r[c] = p;
  }
  if (lane == 0) {
    float s = 0.f, ds = 0.f;
#pragma unroll
    for (int c = 0; c < 10; ++c) {
      h2[(size_t)gw * 10 + c] = r[c];
      s += r[c] * a_src[c];
      ds += r[c] * a_dst[c];
    }
    as2[gw] = s;
    ad2[gw] = ds;
  }
}

// ---------------- conv2 aggregation: 4 nodes per wave, 16 lanes per node ----------------

__global__ __launch_bounds__(256) void k_conv2(const int* __restrict__ off,
                                               const int* __restrict__ adj,
                                               const float* __restrict__ h2,
                                               const float* __restrict__ as2,
                                               const float* __restrict__ ad2,
                                               const float* __restrict__ b2,
                                               float* __restrict__ out, int n) {
  int wid = (blockIdx.x * 256 + threadIdx.x) >> 6;
  int lane = threadIdx.x & 63;
  int grp = lane >> 4;
  int l16 = lane & 15;
  int node = wid * 4 + grp;
  bool active = node < n;
  int beg = 0, end = 0;
  float adv = 0.f;
  if (active) {
    beg = off[node];
    end = off[node + 1];
    adv = ad2[node];
  }
  float m = -1e30f, z = 0.f;
  for (int e = beg + l16; e < end; e += 16) {
    int s = adj[e];
    float v = as2[s] + adv;
    v = v > 0.f ? v : 0.2f * v;
    float nm = fmaxf(m, v);
    z = z * __expf(m - nm) + __expf(v - nm);
    m = nm;
  }
#pragma unroll
  for (int d = 1; d < 16; d <<= 1) {
    float om = __shfl_xor(m, d), oz = __shfl_xor(z, d);
    float nm = fmaxf(m, om);
    z = z * __expf(m - nm) + oz * __expf(om - nm);
    m = nm;
  }
  float inv = 1.0f / (z + 1e-16f);
  float acc[10] = {};
  for (int e = beg + l16; e < end; e += 16) {
    int s = adj[e];
    float v = as2[s] + adv;
    v = v > 0.f ? v : 0.2f * v;
    float wgt = __expf(v - m) * inv;
    const float2* hp = (const float2*)&h2[(size_t)s * 10];
    float2 h01 = hp[0], h23 = hp[1], h45 = hp[2], h67 = hp[3], h89 = hp[4];
    acc[0] += wgt * h01.x; acc[1] += wgt * h01.y;
    acc[2] += wgt * h23.x; acc[3] += wgt * h23.y;
    acc[4] += wgt * h45.x; acc[5] += wgt * h45.y;
    acc[6] += wgt * h67.x; acc[7] += wgt * h67.y;
    acc[8] += wgt * h89.x; acc[9] += wgt * h89.y;
  }
#pragma unroll
  for (int c = 0; c < 10; ++c) {
#pragma unroll
    for (int d = 1; d < 16; d <<= 1) acc[c] += __shfl_xor(acc[c], d);
  }
  if (active && l16 == 0) {
#pragma unroll
    for (int c = 0; c < 10; ++c) out[(size_t)node * 10 + c] = acc[c] + b2[c];
  }
}

// ---------------- launch ----------------

extern "C" void kernel_launch(void* const* d_in, const int* in_sizes, int n_in,
                              void* d_out, int out_size, void* d_ws, size_t ws_size,
                              hipStream_t stream) {
  const float* x      = (const float*)d_in[0];
  const int* ei       = (const int*)d_in[1];
  const float* W1     = (const float*)d_in[2];
  const float* a_src1 = (const float*)d_in[3];
  const float* a_dst1 = (const float*)d_in[4];
  const float* b1     = (const float*)d_in[5];
  const float* W2     = (const float*)d_in[6];
  const float* a_src2 = (const float*)d_in[7];
  const float* a_dst2 = (const float*)d_in[8];
  const float* b2     = (const float*)d_in[9];
  float* out = (float*)d_out;
  const int N = in_sizes[0] / 128;
  const int E = in_sizes[1] / 2;

  char* ws = (char*)d_ws;
  size_t o = 0;
  auto alloc = [&](size_t bytes) -> void* {
    void* p = ws + o;
    o += (bytes + 255) & ~(size_t)255;
    return p;
  };
  int* cnt    = (int*)alloc((size_t)N * 4);
  int* cursor = (int*)alloc((size_t)N * 4);
  int* offs   = (int*)alloc((size_t)(N + 1) * 4);
  int* bsum   = (int*)alloc(1024 * 4);
  int* adj    = (int*)alloc((size_t)(E + N) * 4);
  float* h1   = (float*)alloc((size_t)N * 128 * 4);
  float* a_s1 = (float*)alloc((size_t)N * 4 * 4);
  float* a_d1 = (float*)alloc((size_t)N * 4 * 4);
  float* x2   = (float*)alloc((size_t)N * 128 * 4);
  float* h2   = (float*)alloc((size_t)N * 10 * 4);
  float* a_s2 = (float*)alloc((size_t)N * 4);
  float* a_d2 = (float*)alloc((size_t)N * 4);

  int nb = (N + 1023) / 1024;
  k_init<<<(N + 255) / 256, 256, 0, stream>>>(cnt, cursor, N);
  k_count<<<(E + 255) / 256, 256, 0, stream>>>(ei, cnt, E);
  k_bsum<<<nb, 1024, 0, stream>>>(cnt, bsum, N);
  k_scanb<<<1, 64, 0, stream>>>(bsum, offs, nb, N);
  k_scanc<<<nb, 1024, 0, stream>>>(cnt, bsum, offs, N);
  k_scatter<<<(E + N + 255) / 256, 256, 0, stream>>>(ei, offs, cursor, adj, E, N);
  int g1 = (N + 63) / 64;  // one block per 64-row tile
  k_gemm1<<<g1, 256, 0, stream>>>(x, W1, a_src1, a_dst1, h1, a_s1, a_d1, N);
  k_conv1<<<(N + 15) / 16, 256, 0, stream>>>(offs, adj, h1, a_s1, a_d1, b1, x2, N);
  k_gemm2<<<(N + 3) / 4, 256, 0, stream>>>(x2, W2, a_src2, a_dst2, h2, a_s2, a_d2, N);
  k_conv2<<<(N + 15) / 16, 256, 0, stream>>>(offs, adj, h2, a_s2, a_d2, b2, out, N);
}